// Round 5
// baseline (423.819 us; speedup 1.0000x reference)
//
#include <hip/hip_runtime.h>
#include <stdint.h>

// SCC (sliding-channel conv) = 8 dense group-GEMMs (o%8==g reads channel band
// [128g,128g+256) mod 1024). bf16 MFMA 16x16x32.
// R7: NO LDS AT ALL. W (64 KB/g, bf16) is read per-fragment straight from a
// packed workspace image -- it is L2/LLC-permanent (784 blocks/g read the
// same image). Removes: 2-blocks/CU LDS cap, staging phase, barrier, all
// ds traffic. Kernel is straight-line: issue x loads, then k-loop of
// {afrag global load (L2-hot) + f2bf + MFMA}.
//   - wp layout: fragment-major. Slot (kb*8+mf) = 1024 B holding all 64
//     lanes' 16 B A-frags contiguously (addr = wp_g + slot*1024 + lane*16):
//     each afrag wave-load is ONE contiguous 1024 B line, identical across
//     waves (L2 broadcast-friendly).
//   - __launch_bounds__(256,3): 3 blocks/CU (12 waves). Per XCD: 12 tiles
//     x 8 g in flight -> x working set 3 MB < 4 MB L2, g-partner dedup local.
//   - XCD co-location kept: id = 64*(t/8) + 8*g + (t%8) => id%8 = t%8.
//   - Block = M128 x N64 full-K (R5 showed M-splitting doubles HBM fetch).

#define B_      16
#define C_IN    1024
#define C_OUT   1024
#define UNIT    256
#define STRIDE_ 128
#define HW      3136
#define NT      64              // spatial tile: 3136 = 49*64 exact
#define NTILES  (49 * B_)       // 784 tiles

typedef __attribute__((ext_vector_type(8))) short bf16x8;
typedef __attribute__((ext_vector_type(4))) float floatx4;
typedef __attribute__((ext_vector_type(4))) short short4v;

__device__ __forceinline__ short f2bf(float f) {
    // fp32 -> bf16, round-to-nearest-even
    uint32_t u = __float_as_uint(f);
    u += 0x7FFFu + ((u >> 16) & 1u);
    return (short)(u >> 16);
}

// ---- prologue: W [1024][256] fp32 -> d_ws, 8 x 64KB fragment-major images.
// Image g: slot (kb*8+mf) (1024 B) holds lane (quad*16+nq)'s 16 B fragment
//   = W_bf16[o = g + 8*(mf*16+nq)][k = kb*32 + quad*8 .. +8].
__global__ __launch_bounds__(256) void w_pack_kernel(
    const float* __restrict__ w, short* __restrict__ wp)
{
    int t   = blockIdx.x * 256 + threadIdx.x;   // 65536 threads x 4 floats
    int o   = t >> 6;                           // 0..1023
    int kk4 = (t & 63) << 2;                    // 0..252, 4-float granule
    int g = o & 7, m = o >> 3;                  // m 0..127
    int mf = m >> 4, nq = m & 15;
    int kb = kk4 >> 5, quad = (kk4 >> 3) & 3, j0 = kk4 & 7;  // j0 = 0 or 4
    float4 v = *(const float4*)(w + ((size_t)o << 8) + kk4);
    short4v s4 = { f2bf(v.x), f2bf(v.y), f2bf(v.z), f2bf(v.w) };
    char* dst = (char*)wp + ((size_t)g << 16)
              + ((kb * 8 + mf) << 10) + ((quad * 16 + nq) << 4) + (j0 << 1);
    *(short4v*)dst = s4;
}

template <bool PRE>
__global__ __launch_bounds__(256, 3) void scc_mfma_kernel(
    const float* __restrict__ x, const float* __restrict__ w,
    const short* __restrict__ wp, float* __restrict__ out)
{
    const int tid  = threadIdx.x;
    const int lane = tid & 63;
    const int wn   = tid >> 6;       // wave = one 16-wide N strip
    const int nq   = lane & 15;      // MFMA n-col / A-row index
    const int quad = lane >> 4;      // MFMA k-group

    // XCD co-location decode: id = 64*(t/8) + 8*g + (t%8)
    const int id  = blockIdx.x;
    const int g   = (id >> 3) & 7;
    const int t   = ((id >> 6) << 3) + (id & 7);   // 0..783
    const int b   = t / 49;
    const int px  = t - b * 49;

    const int    p  = px * NT + wn * 16 + nq;
    const float* xb = x + (size_t)b * C_IN * HW + p;

    // ---- issue all 64 x loads (no barrier anywhere; compiler schedules
    // freely against the k-loop)
    float bv[8][8];
#pragma unroll
    for (int kb = 0; kb < 8; ++kb) {
        int cb = (g * STRIDE_ + kb * 32 + quad * 8) & (C_IN - 1);
        const float* xp = xb + (size_t)cb * HW;
#pragma unroll
        for (int j = 0; j < 8; ++j) bv[kb][j] = xp[(size_t)j * HW];
    }

    floatx4 acc[8];
#pragma unroll
    for (int i = 0; i < 8; ++i) acc[i] = (floatx4){0.f, 0.f, 0.f, 0.f};

    const char* wfrag = nullptr;
    if (PRE) wfrag = (const char*)wp + ((size_t)g << 16) + lane * 16;

    // ---- k-loop: 8 k-steps of 32; A-frags straight from L2-hot image
#pragma unroll
    for (int kb = 0; kb < 8; ++kb) {
        bf16x8 bfrag;
#pragma unroll
        for (int j = 0; j < 8; ++j) bfrag[j] = f2bf(bv[kb][j]);
        if (PRE) {
#pragma unroll
            for (int mf = 0; mf < 8; ++mf) {
                bf16x8 afrag = *(const bf16x8*)(wfrag + ((kb * 8 + mf) << 10));
                acc[mf] = __builtin_amdgcn_mfma_f32_16x16x32_bf16(afrag, bfrag, acc[mf], 0, 0, 0);
            }
        } else {
            // fallback: convert fp32 W per fragment (ws too small)
#pragma unroll
            for (int mf = 0; mf < 8; ++mf) {
                const float* wrow = w + (size_t)(g + 8 * (mf * 16 + nq)) * UNIT
                                  + kb * 32 + quad * 8;
                float4 a0 = ((const float4*)wrow)[0];
                float4 a1 = ((const float4*)wrow)[1];
                bf16x8 afrag = { f2bf(a0.x), f2bf(a0.y), f2bf(a0.z), f2bf(a0.w),
                                 f2bf(a1.x), f2bf(a1.y), f2bf(a1.z), f2bf(a1.w) };
                acc[mf] = __builtin_amdgcn_mfma_f32_16x16x32_bf16(afrag, bfrag, acc[mf], 0, 0, 0);
            }
        }
    }

    // ---- epilogue: D col = nq (=p), row = quad*4 + reg within each 16-block;
    // o = g + 8*(mf*16 + quad*4 + reg) = g + 128*mf + 32*quad + 8*reg
    float* ob = out + ((size_t)b * C_OUT + g + 32 * quad) * HW + p;
#pragma unroll
    for (int mf = 0; mf < 8; ++mf) {
        float* o2 = ob + (size_t)(128 * mf) * HW;
#pragma unroll
        for (int reg = 0; reg < 4; ++reg)
            o2[(size_t)(8 * reg) * HW] = acc[mf][reg];
    }
}

extern "C" void kernel_launch(void* const* d_in, const int* in_sizes, int n_in,
                              void* d_out, int out_size, void* d_ws, size_t ws_size,
                              hipStream_t stream)
{
    const float* x = (const float*)d_in[0];
    const float* w = (const float*)d_in[1];
    float* out = (float*)d_out;

    dim3 grid(NTILES * 8);   // 6272 blocks; id = 64*(t/8) + 8*g + (t%8)
    if (d_ws && ws_size >= (size_t)524288) {
        short* wp = (short*)d_ws;
        w_pack_kernel<<<dim3(256), 256, 0, stream>>>(w, wp);
        scc_mfma_kernel<true><<<grid, 256, 0, stream>>>(x, w, wp, out);
    } else {
        scc_mfma_kernel<false><<<grid, 256, 0, stream>>>(x, w, (const short*)nullptr, out);
    }
}

// Round 6
// 355.207 us; speedup vs baseline: 1.1932x; 1.1932x over previous
//
#include <hip/hip_runtime.h>
#include <stdint.h>

// SCC (sliding-channel conv) = 8 dense group-GEMMs (o%8==g reads channel band
// [128g,128g+256) mod 1024). bf16 MFMA 16x16x32.
// R8 = R6 structure + PINNED x-load queue.
//   R7 diagnosis: VGPR_Count=40 proved hipcc sinks plain-C loads to just-
//   before-use -> per-kb serial HBM latency. Fix: 64 volatile inline-asm
//   global_load_dword into dedicated VGPRs (compiler cannot sink/shrink),
//   consumed under hand-counted s_waitcnt vmcnt(56..0) whose asm takes the
//   8 consumed regs as "+v" operands (data-dep: consumers can't hoist).
//   Protocol: W staging (compiler-managed, self-draining) -> sched_barrier
//   wall -> 64 asm x loads (only vmem in flight; counts exact) ->
//   lgkmcnt(0) + raw s_barrier -> k-loop {vmcnt(N) pin, f2bf, ds_read, MFMA}.
//   Kept from R6: zero-conflict chunked LDS W image (4x16KB chunks, 128B
//   rows, 16B slots XOR (m&7)); XCD co-location id=64*(t/8)+8*g+(t%8);
//   M128xN64 full-M block (R5: M-split doubles HBM fetch).

#define B_      16
#define C_IN    1024
#define C_OUT   1024
#define UNIT    256
#define STRIDE_ 128
#define HW      3136
#define NT      64              // spatial tile: 3136 = 49*64 exact
#define NTILES  (49 * B_)       // 784 tiles

typedef __attribute__((ext_vector_type(8))) short bf16x8;
typedef __attribute__((ext_vector_type(4))) float floatx4;
typedef __attribute__((ext_vector_type(4))) short short4v;

__device__ __forceinline__ short f2bf(float f) {
    // fp32 -> bf16, round-to-nearest-even
    uint32_t u = __float_as_uint(f);
    u += 0x7FFFu + ((u >> 16) & 1u);
    return (short)(u >> 16);
}

// ---- prologue: W [1024][256] fp32 -> d_ws, 8 x 64KB swizzled bf16 images.
// Image g: 4 chunks of 16 KB (chunk c = k in [64c,64c+64)); row m (o=g+8m)
// is 128 B = 8 x 16 B segments; segment s at slot (s ^ (m&7)).
// Layout measured ZERO bank conflicts (R4/R5/R6).
__global__ __launch_bounds__(256) void w_pack_kernel(
    const float* __restrict__ w, short* __restrict__ wp)
{
    int t   = blockIdx.x * 256 + threadIdx.x;   // 65536 threads x 4 floats
    int o   = t >> 6;                           // 0..1023
    int kk4 = (t & 63) << 2;                    // 0..252
    int g = o & 7, m = o >> 3;
    float4 v = *(const float4*)(w + ((size_t)o << 8) + kk4);
    short4v s4 = { f2bf(v.x), f2bf(v.y), f2bf(v.z), f2bf(v.w) };
    int c   = kk4 >> 6;                         // chunk 0..3
    int seg = (kk4 >> 3) & 7;                   // 16B segment within chunk row
    char* dst = (char*)wp + ((size_t)g << 16) + (c << 14) + (m << 7)
              + (((seg ^ (m & 7)) << 4) | ((kk4 & 4) << 1));
    *(short4v*)dst = s4;
}

// wait for all but N outstanding vmem ops; pins the 8 regs consumed next so
// their consumers cannot be scheduled above this wait (data dependence).
#define WAIT_PIN(N, KB)                                                       \
    asm volatile("s_waitcnt vmcnt(" #N ")"                                    \
        : "+v"(bv[KB][0]), "+v"(bv[KB][1]), "+v"(bv[KB][2]), "+v"(bv[KB][3]), \
          "+v"(bv[KB][4]), "+v"(bv[KB][5]), "+v"(bv[KB][6]), "+v"(bv[KB][7])  \
        :: "memory")

template <bool PRE>
__global__ __launch_bounds__(256, 2) void scc_mfma_kernel(
    const float* __restrict__ x, const float* __restrict__ w,
    const short* __restrict__ wp, float* __restrict__ out)
{
    __shared__ short Ws[128 * 256];  // 64 KB: 4 chunks x (128 rows x 128 B)

    const int tid  = threadIdx.x;
    const int lane = tid & 63;
    const int wn   = tid >> 6;       // wave = one 16-wide N strip
    const int nq   = lane & 15;      // MFMA n-col / A-row index
    const int quad = lane >> 4;      // MFMA k-group

    // XCD co-location decode: id = 64*(t/8) + 8*g + (t%8) => id%8 = t%8
    const int id  = blockIdx.x;
    const int g   = (id >> 3) & 7;
    const int t   = ((id >> 6) << 3) + (id & 7);   // 0..783
    const int b   = t / 49;
    const int px  = t - b * 49;

    const int    p  = px * NT + wn * 16 + nq;
    const float* xb = x + (size_t)b * C_IN * HW + p;
    char* wsb = (char*)Ws;

    if (PRE) {
        // ---- 1. W staging: compiler-managed; its vmcnt bookkeeping closes
        // at the last ds_write (all wtmp loads drained before the wall).
        const char* wsrc = (const char*)wp + ((size_t)g << 16);
        int4 wtmp[16];
#pragma unroll
        for (int i = 0; i < 16; ++i)
            wtmp[i] = *(const int4*)(wsrc + i * 4096 + tid * 16);
#pragma unroll
        for (int i = 0; i < 16; ++i)
            *(int4*)(wsb + i * 4096 + tid * 16) = wtmp[i];
        __builtin_amdgcn_sched_barrier(0);   // wall: no vmem crosses

        // ---- 2. the ONLY vmem now issued: 64 pinned asm x loads
        float bv[8][8];
#pragma unroll
        for (int kb = 0; kb < 8; ++kb) {
            int cb = (g * STRIDE_ + kb * 32 + quad * 8) & (C_IN - 1);
            const float* xp = xb + (size_t)cb * HW;
#pragma unroll
            for (int j = 0; j < 8; ++j)
                asm volatile("global_load_dword %0, %1, off"
                             : "=v"(bv[kb][j])
                             : "v"(xp + (size_t)j * HW)
                             : "memory");
        }

        // ---- 3. raw barrier: LDS writes visible; x queue NOT drained
        asm volatile("s_waitcnt lgkmcnt(0)" ::: "memory");
        __builtin_amdgcn_s_barrier();
        __builtin_amdgcn_sched_barrier(0);

        floatx4 acc[8];
#pragma unroll
        for (int i = 0; i < 8; ++i) acc[i] = (floatx4){0.f, 0.f, 0.f, 0.f};

        // ---- 4. k-loop: per kb wait for exactly its 8 oldest loads
        auto kstep = [&](int kb) {
            bf16x8 bfrag;
#pragma unroll
            for (int j = 0; j < 8; ++j) bfrag[j] = f2bf(bv[kb][j]);
            const int aoff = (kb >> 1) * 16384 + nq * 128
                           + ((((kb & 1) * 4 + quad) ^ (nq & 7)) << 4);
#pragma unroll
            for (int mf = 0; mf < 8; ++mf) {
                bf16x8 afrag = *(const bf16x8*)(wsb + mf * 2048 + aoff);
                acc[mf] = __builtin_amdgcn_mfma_f32_16x16x32_bf16(afrag, bfrag, acc[mf], 0, 0, 0);
            }
        };
        WAIT_PIN(56, 0); kstep(0);
        WAIT_PIN(48, 1); kstep(1);
        WAIT_PIN(40, 2); kstep(2);
        WAIT_PIN(32, 3); kstep(3);
        WAIT_PIN(24, 4); kstep(4);
        WAIT_PIN(16, 5); kstep(5);
        WAIT_PIN(8,  6); kstep(6);
        WAIT_PIN(0,  7); kstep(7);

        // ---- epilogue: o = g + 128*mf + 32*quad + 8*reg, col p
        float* ob = out + ((size_t)b * C_OUT + g + 32 * quad) * HW + p;
#pragma unroll
        for (int mf = 0; mf < 8; ++mf) {
            float* o2 = ob + (size_t)(128 * mf) * HW;
#pragma unroll
            for (int reg = 0; reg < 4; ++reg)
                o2[(size_t)(8 * reg) * HW] = acc[mf][reg];
        }
    } else {
        // ---- fallback (ws too small): in-kernel W convert, plain barrier
        float bv[8][8];
#pragma unroll
        for (int kb = 0; kb < 8; ++kb) {
            int cb = (g * STRIDE_ + kb * 32 + quad * 8) & (C_IN - 1);
            const float* xp = xb + (size_t)cb * HW;
#pragma unroll
            for (int j = 0; j < 8; ++j) bv[kb][j] = xp[(size_t)j * HW];
        }
#pragma unroll
        for (int r = 0; r < 32; ++r) {
            int f   = tid + 256 * r;          // 0..8191 float4s
            int m   = f >> 6;                 // 0..127
            int kk4 = (f & 63) << 2;          // 0..252
            float4 v = *(const float4*)(w + (size_t)(g + 8 * m) * UNIT + kk4);
            short4v s4 = { f2bf(v.x), f2bf(v.y), f2bf(v.z), f2bf(v.w) };
            int c   = kk4 >> 6;
            int seg = (kk4 >> 3) & 7;
            *(short4v*)(wsb + (c << 14) + (m << 7)
                        + (((seg ^ (m & 7)) << 4) | ((kk4 & 4) << 1))) = s4;
        }
        __syncthreads();

        floatx4 acc[8];
#pragma unroll
        for (int i = 0; i < 8; ++i) acc[i] = (floatx4){0.f, 0.f, 0.f, 0.f};
#pragma unroll
        for (int kb = 0; kb < 8; ++kb) {
            bf16x8 bfrag;
#pragma unroll
            for (int j = 0; j < 8; ++j) bfrag[j] = f2bf(bv[kb][j]);
            const int aoff = (kb >> 1) * 16384 + nq * 128
                           + ((((kb & 1) * 4 + quad) ^ (nq & 7)) << 4);
#pragma unroll
            for (int mf = 0; mf < 8; ++mf) {
                bf16x8 afrag = *(const bf16x8*)(wsb + mf * 2048 + aoff);
                acc[mf] = __builtin_amdgcn_mfma_f32_16x16x32_bf16(afrag, bfrag, acc[mf], 0, 0, 0);
            }
        }
        float* ob = out + ((size_t)b * C_OUT + g + 32 * quad) * HW + p;
#pragma unroll
        for (int mf = 0; mf < 8; ++mf) {
            float* o2 = ob + (size_t)(128 * mf) * HW;
#pragma unroll
            for (int reg = 0; reg < 4; ++reg)
                o2[(size_t)(8 * reg) * HW] = acc[mf][reg];
        }
    }
}

extern "C" void kernel_launch(void* const* d_in, const int* in_sizes, int n_in,
                              void* d_out, int out_size, void* d_ws, size_t ws_size,
                              hipStream_t stream)
{
    const float* x = (const float*)d_in[0];
    const float* w = (const float*)d_in[1];
    float* out = (float*)d_out;

    dim3 grid(NTILES * 8);   // 6272 blocks; id = 64*(t/8) + 8*g + (t%8)
    if (d_ws && ws_size >= (size_t)524288) {
        short* wp = (short*)d_ws;
        w_pack_kernel<<<dim3(256), 256, 0, stream>>>(w, wp);
        scc_mfma_kernel<true><<<grid, 256, 0, stream>>>(x, w, wp, out);
    } else {
        scc_mfma_kernel<false><<<grid, 256, 0, stream>>>(x, w, (const short*)nullptr, out);
    }
}